// Round 3
// baseline (248.608 us; speedup 1.0000x reference)
//
#include <hip/hip_runtime.h>
#include <hip/hip_bf16.h>
#include <stdint.h>

typedef __bf16 bf16_t;
typedef __bf16 bf16x8 __attribute__((ext_vector_type(8)));
typedef float f32x4 __attribute__((ext_vector_type(4)));
typedef float f32x16 __attribute__((ext_vector_type(16)));
typedef int i32x2 __attribute__((ext_vector_type(2)));

#define B_ 4
#define N_ 4096
#define C_ 256
#define D3_ 768
// SCALE = 1/sqrt(32); AEXP = SCALE * log2(e)
#define AEXP 0.2550348757f
// defer-max threshold: skip rescale while (mloc-m_run)*AEXP <= 3  (P <= 8)
#define DMTHR 11.763f

__device__ __forceinline__ f32x4 mfma16(bf16x8 a, bf16x8 b, f32x4 c) {
    return __builtin_amdgcn_mfma_f32_16x16x32_bf16(a, b, c, 0, 0, 0);
}
__device__ __forceinline__ f32x16 mfma32(bf16x8 a, bf16x8 b, f32x16 c) {
    return __builtin_amdgcn_mfma_f32_32x32x16_bf16(a, b, c, 0, 0, 0);
}
__device__ __forceinline__ int cvtpk(float lo, float hi) {
    int r; asm("v_cvt_pk_bf16_f32 %0, %1, %2" : "=v"(r) : "v"(lo), "v"(hi)); return r;
}
// Build PV B-operand fragment in-register (T12)
__device__ __forceinline__ bf16x8 mkfrag(float q0, float q1, float q2, float q3,
                                         float q4, float q5, float q6, float q7) {
    int a0 = cvtpk(q0, q1), a1 = cvtpk(q2, q3);
    int b0 = cvtpk(q4, q5), b1 = cvtpk(q6, q7);
    i32x2 r0 = __builtin_amdgcn_permlane32_swap(a0, b0, false, false);
    i32x2 r1 = __builtin_amdgcn_permlane32_swap(a1, b1, false, false);
    union { int i[4]; bf16x8 v; } u;
    u.i[0] = r0.x; u.i[1] = r1.x; u.i[2] = r0.y; u.i[3] = r1.y;
    return u.v;
}
// cross-half (lane ^ 32) reduce helpers via permlane32_swap (VALU, no LDS)
__device__ __forceinline__ float xhalf_max(float v) {
    int iv = __builtin_bit_cast(int, v);
    i32x2 r = __builtin_amdgcn_permlane32_swap(iv, iv, false, false);
    return fmaxf(__builtin_bit_cast(float, r.x), __builtin_bit_cast(float, r.y));
}
__device__ __forceinline__ float xhalf_sum(float v) {
    int iv = __builtin_bit_cast(int, v);
    i32x2 r = __builtin_amdgcn_permlane32_swap(iv, iv, false, false);
    return __builtin_bit_cast(float, r.x) + __builtin_bit_cast(float, r.y);
}

union PK4 { uint2 u2; bf16_t h[4]; };

// ---------------- prep: weight transposes (to B^T layout, bf16) + zero stats ----------------
__global__ void prep_w(const float* __restrict__ wqkv, const float* __restrict__ wproj,
                       bf16_t* __restrict__ Wt, bf16_t* __restrict__ Wpt,
                       float* __restrict__ stats) {
    int t = blockIdx.x * 256 + threadIdx.x;
    if (t < D3_ * C_) {              // Wt[c][k] = wqkv[k][c]
        int c = t >> 8, k = t & 255;
        Wt[t] = (bf16_t)wqkv[k * D3_ + c];
    }
    if (t < C_ * C_) {               // Wpt[c][k] = wproj[k][c]
        int c = t >> 8, k = t & 255;
        Wpt[t] = (bf16_t)wproj[k * C_ + c];
    }
    if (t < B_ * 32 * 2) stats[t] = 0.f;
}

// ---------------- prep: x [B,C,N] f32 -> xT [B,N,C] bf16 (LDS tile transpose) ----------------
__global__ void prep_xt(const float* __restrict__ x, bf16_t* __restrict__ xT) {
    __shared__ float tile[32][33];
    int n0 = blockIdx.x * 32, c0 = blockIdx.y * 32, b = blockIdx.z;
    int t = threadIdx.x;
    int tx = t & 31, ty = t >> 5;
    const float* xp = x + ((size_t)b * C_ + c0) * N_ + n0;
#pragma unroll
    for (int p = 0; p < 4; ++p)
        tile[p * 8 + ty][tx] = xp[(size_t)(p * 8 + ty) * N_ + tx];
    __syncthreads();
    int ci = t & 15, nr0 = t >> 4;
    bf16_t* op = xT + ((size_t)b * N_ + n0) * C_ + c0;
#pragma unroll
    for (int p = 0; p < 2; ++p) {
        int nr = p * 16 + nr0;
        union { uint32_t u; bf16_t h[2]; } pk;
        pk.h[0] = (bf16_t)tile[2 * ci][nr];
        pk.h[1] = (bf16_t)tile[2 * ci + 1][nr];
        *reinterpret_cast<uint32_t*>(op + (size_t)nr * C_ + 2 * ci) = pk.u;
    }
}

// ---------------- QKV GEMM: [16384,256]bf16 @ W[256,768] + bias -> scatter Q/K/Vt ----------------
__global__ __launch_bounds__(256) void gemm_qkv(
    const bf16_t* __restrict__ xT, const bf16_t* __restrict__ Wt,
    const float* __restrict__ bqkv,
    bf16_t* __restrict__ Q, bf16_t* __restrict__ K, bf16_t* __restrict__ Vt)
{
    __shared__ __align__(16) bf16_t Al[64][40];
    __shared__ __align__(16) bf16_t Bl[64][40];
    int m0 = blockIdx.x * 64, c0 = blockIdx.y * 64;
    int t = threadIdx.x;
    int w = t >> 6, l = t & 63, li = l & 15, lg = l >> 4;
    int srow = t >> 2, scol = (t & 3) * 8;
    f32x4 acc[4] = {};
    for (int k0 = 0; k0 < C_; k0 += 32) {
        *reinterpret_cast<bf16x8*>(&Al[srow][scol]) =
            *reinterpret_cast<const bf16x8*>(&xT[(size_t)(m0 + srow) * C_ + k0 + scol]);
        *reinterpret_cast<bf16x8*>(&Bl[srow][scol]) =
            *reinterpret_cast<const bf16x8*>(&Wt[(size_t)(c0 + srow) * C_ + k0 + scol]);
        __syncthreads();
        bf16x8 af = *reinterpret_cast<const bf16x8*>(&Al[w * 16 + li][lg * 8]);
#pragma unroll
        for (int ct = 0; ct < 4; ++ct) {
            bf16x8 bf = *reinterpret_cast<const bf16x8*>(&Bl[ct * 16 + li][lg * 8]);
            acc[ct] = mfma16(af, bf, acc[ct]);
        }
        __syncthreads();
    }
    int mb = m0 + w * 16 + lg * 4;
    int b = mb >> 12, n = mb & 4095;
#pragma unroll
    for (int ct = 0; ct < 4; ++ct) {
        int col = c0 + ct * 16 + li;
        float bias = bqkv[col];
        int sec = col >> 8, cc = col & 255;
        int h = cc >> 5, d = cc & 31;
        if (sec == 2) {              // V stored transposed: Vt[b,h][d][n]
            PK4 pk;
#pragma unroll
            for (int r = 0; r < 4; ++r) pk.h[r] = (bf16_t)(acc[ct][r] + bias);
            *reinterpret_cast<uint2*>(&Vt[((size_t)((b << 3) + h) * 32 + d) * N_ + n]) = pk.u2;
        } else {                     // Q / K: [b,h][n][d]
            bf16_t* dst = (sec == 0) ? Q : K;
            size_t base = ((size_t)((b << 3) + h) * N_ + n) * 32 + d;
#pragma unroll
            for (int r = 0; r < 4; ++r) dst[base + (size_t)r * 32] = (bf16_t)(acc[ct][r] + bias);
        }
    }
}

// ---------------- flash attention: 32x32 MFMA, in-register P (T12), defer-max (T13) ----------------
__global__ __launch_bounds__(256) void attn(
    const bf16_t* __restrict__ Q, const bf16_t* __restrict__ Kg,
    const bf16_t* __restrict__ Vt, bf16_t* __restrict__ O)
{
    __shared__ __align__(16) bf16_t Kl[64][36];   // K[j][d]
    __shared__ __align__(16) bf16_t Vl[32][68];   // V^T[d][j]
    int id = blockIdx.x;
    int wg = (id & 7) * 128 + (id >> 3);          // XCD swizzle
    int bh = wg >> 5, qb = wg & 31;
    int t = threadIdx.x, w = t >> 6, l = t & 63;
    int lo = l & 31, hi = l >> 5;
    const bf16_t* Qp = Q + (size_t)bh * N_ * 32;
    const bf16_t* Kp = Kg + (size_t)bh * N_ * 32;
    const bf16_t* Vp = Vt + (size_t)bh * 32 * N_;
    int qrow = qb * 128 + w * 32 + lo;
    bf16x8 qf0 = *reinterpret_cast<const bf16x8*>(&Qp[(size_t)qrow * 32 + hi * 8]);
    bf16x8 qf1 = *reinterpret_cast<const bf16x8*>(&Qp[(size_t)qrow * 32 + 16 + hi * 8]);
    f32x16 oacc = {};
    float m_run = -INFINITY, l_run = 0.f;
    int krow = t >> 2, kcol = (t & 3) * 8;
    int vrow = t >> 3, vcol = (t & 7) * 8;
    const bf16_t* kgp = Kp + (size_t)krow * 32 + kcol;
    const bf16_t* vgp = Vp + (size_t)vrow * N_ + vcol;
    bf16x8 kreg = *reinterpret_cast<const bf16x8*>(kgp);
    bf16x8 vreg = *reinterpret_cast<const bf16x8*>(vgp);
    for (int n0 = 0; n0 < N_; n0 += 64) {
        *reinterpret_cast<bf16x8*>(&Kl[krow][kcol]) = kreg;
        *reinterpret_cast<bf16x8*>(&Vl[vrow][vcol]) = vreg;
        __syncthreads();
        if (n0 + 64 < N_) {                       // issue next tile's loads early (T14)
            kgp += 64 * 32; vgp += 64;
            kreg = *reinterpret_cast<const bf16x8*>(kgp);
            vreg = *reinterpret_cast<const bf16x8*>(vgp);
        }
        // QK^T: S^T[j][i]  (j = crow(reg,hi) + 32*jt, i = lo)
        f32x16 st0 = {}, st1 = {};
        bf16x8 kf0 = *reinterpret_cast<const bf16x8*>(&Kl[lo][hi * 8]);
        bf16x8 kf1 = *reinterpret_cast<const bf16x8*>(&Kl[lo][16 + hi * 8]);
        bf16x8 kf2 = *reinterpret_cast<const bf16x8*>(&Kl[32 + lo][hi * 8]);
        bf16x8 kf3 = *reinterpret_cast<const bf16x8*>(&Kl[32 + lo][16 + hi * 8]);
        __builtin_amdgcn_s_setprio(1);
        st0 = mfma32(kf0, qf0, st0);
        st0 = mfma32(kf1, qf1, st0);
        st1 = mfma32(kf2, qf0, st1);
        st1 = mfma32(kf3, qf1, st1);
        __builtin_amdgcn_s_setprio(0);
        // online softmax over 64 j (32 in-lane x2 + partner half via permlane)
        float mloc = -INFINITY;
#pragma unroll
        for (int u = 0; u < 16; ++u) mloc = fmaxf(mloc, fmaxf(st0[u], st1[u]));  // v_max3
        mloc = xhalf_max(mloc);
        // defer-max (T13): only rescale when the running max moved materially
        if (!__all(mloc - m_run <= DMTHR)) {
            float m_new = fmaxf(m_run, mloc);
            float alpha = __builtin_amdgcn_exp2f((m_run - m_new) * AEXP);
            m_run = m_new;
            l_run *= alpha;
#pragma unroll
            for (int u = 0; u < 16; ++u) oacc[u] *= alpha;
        }
        float msc = m_run * AEXP;
        float lsum = 0.f;
#pragma unroll
        for (int u = 0; u < 16; ++u) {
            st0[u] = __builtin_amdgcn_exp2f(fmaf(st0[u], AEXP, -msc));
            st1[u] = __builtin_amdgcn_exp2f(fmaf(st1[u], AEXP, -msc));
            lsum += st0[u] + st1[u];
        }
        l_run += xhalf_sum(lsum);
        // P fragments (no LDS round-trip)
        bf16x8 pf0 = mkfrag(st0[0], st0[1], st0[2], st0[3], st0[4], st0[5], st0[6], st0[7]);
        bf16x8 pf1 = mkfrag(st0[8], st0[9], st0[10], st0[11], st0[12], st0[13], st0[14], st0[15]);
        bf16x8 pf2 = mkfrag(st1[0], st1[1], st1[2], st1[3], st1[4], st1[5], st1[6], st1[7]);
        bf16x8 pf3 = mkfrag(st1[8], st1[9], st1[10], st1[11], st1[12], st1[13], st1[14], st1[15]);
        // PV: O^T[d][i] += V^T[d][j] * P^T[j][i]
        bf16x8 vf0 = *reinterpret_cast<const bf16x8*>(&Vl[lo][hi * 8]);
        bf16x8 vf1 = *reinterpret_cast<const bf16x8*>(&Vl[lo][16 + hi * 8]);
        bf16x8 vf2 = *reinterpret_cast<const bf16x8*>(&Vl[lo][32 + hi * 8]);
        bf16x8 vf3 = *reinterpret_cast<const bf16x8*>(&Vl[lo][48 + hi * 8]);
        __builtin_amdgcn_s_setprio(1);
        oacc = mfma32(vf0, pf0, oacc);
        oacc = mfma32(vf1, pf1, oacc);
        oacc = mfma32(vf2, pf2, oacc);
        oacc = mfma32(vf3, pf3, oacc);
        __builtin_amdgcn_s_setprio(0);
        __syncthreads();
    }
    // epilogue: O^T[d][i] / l(i) -> O[b][n][h*32+d]; d = rq*8 + hi*4 + (reg&3)
    float inv_l = 1.f / l_run;
    int b = bh >> 3, h = bh & 7;
#pragma unroll
    for (int rq = 0; rq < 4; ++rq) {
        PK4 pk;
#pragma unroll
        for (int r = 0; r < 4; ++r) pk.h[r] = (bf16_t)(oacc[rq * 4 + r] * inv_l);
        int d = rq * 8 + hi * 4;
        *reinterpret_cast<uint2*>(&O[(((size_t)b * N_ + qrow) * 8 + h) * 32 + d]) = pk.u2;
    }
}

// ---------------- proj GEMM + bias + residual(x) -> z [B,C,N] f32, + group partial sums ----------------
__global__ __launch_bounds__(256) void gemm_proj(
    const bf16_t* __restrict__ O, const bf16_t* __restrict__ Wpt,
    const float* __restrict__ bproj, const float* __restrict__ x,
    float* __restrict__ z, float* __restrict__ stats)
{
    __shared__ __align__(16) bf16_t Al[64][40];
    __shared__ __align__(16) bf16_t Bl[64][40];
    int m0 = blockIdx.x * 64, c0 = blockIdx.y * 64;
    int t = threadIdx.x;
    int w = t >> 6, l = t & 63, li = l & 15, lg = l >> 4;
    int srow = t >> 2, scol = (t & 3) * 8;
    f32x4 acc[4] = {};
    for (int k0 = 0; k0 < C_; k0 += 32) {
        *reinterpret_cast<bf16x8*>(&Al[srow][scol]) =
            *reinterpret_cast<const bf16x8*>(&O[(size_t)(m0 + srow) * C_ + k0 + scol]);
        *reinterpret_cast<bf16x8*>(&Bl[srow][scol]) =
            *reinterpret_cast<const bf16x8*>(&Wpt[(size_t)(c0 + srow) * C_ + k0 + scol]);
        __syncthreads();
        bf16x8 af = *reinterpret_cast<const bf16x8*>(&Al[w * 16 + li][lg * 8]);
#pragma unroll
        for (int ct = 0; ct < 4; ++ct) {
            bf16x8 bf = *reinterpret_cast<const bf16x8*>(&Bl[ct * 16 + li][lg * 8]);
            acc[ct] = mfma16(af, bf, acc[ct]);
        }
        __syncthreads();
    }
    int mb = m0 + w * 16 + lg * 4;
    int b = mb >> 12, n = mb & 4095;
#pragma unroll
    for (int ct = 0; ct < 4; ++ct) {
        int c = c0 + ct * 16 + li;
        float bias = bproj[c];
        size_t xoff = ((size_t)b * C_ + c) * N_ + n;
        f32x4 xv = *reinterpret_cast<const f32x4*>(&x[xoff]);
        f32x4 zv;
        float s = 0.f, s2 = 0.f;
#pragma unroll
        for (int r = 0; r < 4; ++r) {
            float v = acc[ct][r] + bias + xv[r];
            zv[r] = v; s += v; s2 += v * v;
        }
        *reinterpret_cast<f32x4*>(&z[xoff]) = zv;
        s  += __shfl_xor(s, 16, 64);  s  += __shfl_xor(s, 32, 64);
        s2 += __shfl_xor(s2, 16, 64); s2 += __shfl_xor(s2, 32, 64);
        s  += __shfl_xor(s, 1, 64);  s  += __shfl_xor(s, 2, 64);  s  += __shfl_xor(s, 4, 64);
        s2 += __shfl_xor(s2, 1, 64); s2 += __shfl_xor(s2, 2, 64); s2 += __shfl_xor(s2, 4, 64);
        if (lg == 0 && (li & 7) == 0) {
            int g = c >> 3;
            atomicAdd(&stats[((b << 5) + g) * 2 + 0], s);
            atomicAdd(&stats[((b << 5) + g) * 2 + 1], s2);
        }
    }
}

// ---------------- GroupNorm normalize: z [B,C,N] -> out [B,C,H,W] ----------------
__global__ void gnorm(const float* __restrict__ z, const float* __restrict__ stats,
                      const float* __restrict__ gamma, const float* __restrict__ beta,
                      float* __restrict__ out)
{
    size_t idx = ((size_t)blockIdx.x * 256 + threadIdx.x) * 4;
    int b = (int)(idx >> 20);
    int c = (int)((idx >> 12) & 255);
    int g = c >> 3;
    float s = stats[((b << 5) + g) * 2], s2 = stats[((b << 5) + g) * 2 + 1];
    const float inv = 1.f / 32768.f;
    float mean = s * inv;
    float var = s2 * inv - mean * mean;
    float rs = rsqrtf(var + 1e-5f);
    float ga = gamma[c] * rs;
    float be = beta[c];
    f32x4 v = *reinterpret_cast<const f32x4*>(&z[idx]);
    f32x4 o;
#pragma unroll
    for (int r = 0; r < 4; ++r) o[r] = (v[r] - mean) * ga + be;
    *reinterpret_cast<f32x4*>(&out[idx]) = o;
}

extern "C" void kernel_launch(void* const* d_in, const int* in_sizes, int n_in,
                              void* d_out, int out_size, void* d_ws, size_t ws_size,
                              hipStream_t stream) {
    (void)in_sizes; (void)n_in; (void)out_size; (void)ws_size;
    const float* x     = (const float*)d_in[0];
    const float* wqkv  = (const float*)d_in[1];
    const float* bqkv  = (const float*)d_in[2];
    const float* wproj = (const float*)d_in[3];
    const float* bproj = (const float*)d_in[4];
    const float* gamma = (const float*)d_in[5];
    const float* beta  = (const float*)d_in[6];
    float* out = (float*)d_out;

    char* ws = (char*)d_ws;
    const size_t SZ_BNC2 = (size_t)B_ * N_ * C_ * 2;
    size_t off = 0;
    bf16_t* xT  = (bf16_t*)(ws + off); off += SZ_BNC2;
    bf16_t* Wt  = (bf16_t*)(ws + off); off += (size_t)D3_ * C_ * 2;
    bf16_t* Qb  = (bf16_t*)(ws + off); off += SZ_BNC2;
    bf16_t* Kb  = (bf16_t*)(ws + off); off += SZ_BNC2;
    bf16_t* Vtb = (bf16_t*)(ws + off); off += SZ_BNC2;
    bf16_t* Ob  = (bf16_t*)(ws + off); off += SZ_BNC2;
    bf16_t* Wpt = (bf16_t*)(ws + off); off += (size_t)C_ * C_ * 2;
    float*  stats = (float*)(ws + off); off += 1024;
    float* zb = (float*)d_ws;   // aliases xT/Wt/Qb (dead by gemm_proj)

    prep_w <<<768, 256, 0, stream>>>(wqkv, wproj, Wt, Wpt, stats);
    prep_xt<<<dim3(N_ / 32, C_ / 32, B_), 256, 0, stream>>>(x, xT);
    gemm_qkv<<<dim3(256, 12), 256, 0, stream>>>(xT, Wt, bqkv, Qb, Kb, Vtb);
    attn<<<1024, 256, 0, stream>>>(Qb, Kb, Vtb, Ob);
    gemm_proj<<<dim3(256, 4), 256, 0, stream>>>(Ob, Wpt, bproj, x, zb, stats);
    gnorm<<<4096, 256, 0, stream>>>(zb, stats, gamma, beta, out);
}

// Round 4
// 228.754 us; speedup vs baseline: 1.0868x; 1.0868x over previous
//
#include <hip/hip_runtime.h>
#include <hip/hip_bf16.h>
#include <stdint.h>

typedef __bf16 bf16_t;
typedef __bf16 bf16x8 __attribute__((ext_vector_type(8)));
typedef float f32x4 __attribute__((ext_vector_type(4)));
typedef float f32x16 __attribute__((ext_vector_type(16)));
typedef int i32x2 __attribute__((ext_vector_type(2)));

#define B_ 4
#define N_ 4096
#define C_ 256
#define D3_ 768
// SCALE = 1/sqrt(32); AEXP = SCALE * log2(e)
#define AEXP 0.2550348757f
// defer-max threshold: skip rescale while (mloc-m_run)*AEXP <= 3  (P <= 8)
#define DMTHR 11.763f

__device__ __forceinline__ f32x4 mfma16(bf16x8 a, bf16x8 b, f32x4 c) {
    return __builtin_amdgcn_mfma_f32_16x16x32_bf16(a, b, c, 0, 0, 0);
}
__device__ __forceinline__ f32x16 mfma32(bf16x8 a, bf16x8 b, f32x16 c) {
    return __builtin_amdgcn_mfma_f32_32x32x16_bf16(a, b, c, 0, 0, 0);
}
__device__ __forceinline__ int cvtpk(float lo, float hi) {
    int r; asm("v_cvt_pk_bf16_f32 %0, %1, %2" : "=v"(r) : "v"(lo), "v"(hi)); return r;
}
// Build PV B-operand fragment in-register (T12)
__device__ __forceinline__ bf16x8 mkfrag(float q0, float q1, float q2, float q3,
                                         float q4, float q5, float q6, float q7) {
    int a0 = cvtpk(q0, q1), a1 = cvtpk(q2, q3);
    int b0 = cvtpk(q4, q5), b1 = cvtpk(q6, q7);
    i32x2 r0 = __builtin_amdgcn_permlane32_swap(a0, b0, false, false);
    i32x2 r1 = __builtin_amdgcn_permlane32_swap(a1, b1, false, false);
    union { int i[4]; bf16x8 v; } u;
    u.i[0] = r0.x; u.i[1] = r1.x; u.i[2] = r0.y; u.i[3] = r1.y;
    return u.v;
}
// cross-half (lane ^ 32) reduce helpers via permlane32_swap (VALU, no LDS)
__device__ __forceinline__ float xhalf_max(float v) {
    int iv = __builtin_bit_cast(int, v);
    i32x2 r = __builtin_amdgcn_permlane32_swap(iv, iv, false, false);
    return fmaxf(__builtin_bit_cast(float, r.x), __builtin_bit_cast(float, r.y));
}
__device__ __forceinline__ float xhalf_sum(float v) {
    int iv = __builtin_bit_cast(int, v);
    i32x2 r = __builtin_amdgcn_permlane32_swap(iv, iv, false, false);
    return __builtin_bit_cast(float, r.x) + __builtin_bit_cast(float, r.y);
}

union PK4 { uint2 u2; bf16_t h[4]; };

// ---------------- prep: weight transposes (to B^T layout, bf16) + zero stats ----------------
__global__ void prep_w(const float* __restrict__ wqkv, const float* __restrict__ wproj,
                       bf16_t* __restrict__ Wt, bf16_t* __restrict__ Wpt,
                       float* __restrict__ stats) {
    int t = blockIdx.x * 256 + threadIdx.x;
    if (t < D3_ * C_) {              // Wt[c][k] = wqkv[k][c]
        int c = t >> 8, k = t & 255;
        Wt[t] = (bf16_t)wqkv[k * D3_ + c];
    }
    if (t < C_ * C_) {               // Wpt[c][k] = wproj[k][c]
        int c = t >> 8, k = t & 255;
        Wpt[t] = (bf16_t)wproj[k * C_ + c];
    }
    if (t < B_ * 32 * 2) stats[t] = 0.f;
}

// ---------------- prep: x [B,C,N] f32 -> xT [B,N,C] bf16 (LDS tile transpose) ----------------
__global__ void prep_xt(const float* __restrict__ x, bf16_t* __restrict__ xT) {
    __shared__ float tile[32][33];
    int n0 = blockIdx.x * 32, c0 = blockIdx.y * 32, b = blockIdx.z;
    int t = threadIdx.x;
    int tx = t & 31, ty = t >> 5;
    const float* xp = x + ((size_t)b * C_ + c0) * N_ + n0;
#pragma unroll
    for (int p = 0; p < 4; ++p)
        tile[p * 8 + ty][tx] = xp[(size_t)(p * 8 + ty) * N_ + tx];
    __syncthreads();
    int ci = t & 15, nr0 = t >> 4;
    bf16_t* op = xT + ((size_t)b * N_ + n0) * C_ + c0;
#pragma unroll
    for (int p = 0; p < 2; ++p) {
        int nr = p * 16 + nr0;
        union { uint32_t u; bf16_t h[2]; } pk;
        pk.h[0] = (bf16_t)tile[2 * ci][nr];
        pk.h[1] = (bf16_t)tile[2 * ci + 1][nr];
        *reinterpret_cast<uint32_t*>(op + (size_t)nr * C_ + 2 * ci) = pk.u;
    }
}

// ---------------- QKV GEMM: [16384,256]bf16 @ W[256,768] + bias -> scatter Q/K/Vt ----------------
__global__ __launch_bounds__(256) void gemm_qkv(
    const bf16_t* __restrict__ xT, const bf16_t* __restrict__ Wt,
    const float* __restrict__ bqkv,
    bf16_t* __restrict__ Q, bf16_t* __restrict__ K, bf16_t* __restrict__ Vt)
{
    __shared__ __align__(16) bf16_t Al[64][40];
    __shared__ __align__(16) bf16_t Bl[64][40];
    int m0 = blockIdx.x * 64, c0 = blockIdx.y * 64;
    int t = threadIdx.x;
    int w = t >> 6, l = t & 63, li = l & 15, lg = l >> 4;
    int srow = t >> 2, scol = (t & 3) * 8;
    f32x4 acc[4] = {};
    for (int k0 = 0; k0 < C_; k0 += 32) {
        *reinterpret_cast<bf16x8*>(&Al[srow][scol]) =
            *reinterpret_cast<const bf16x8*>(&xT[(size_t)(m0 + srow) * C_ + k0 + scol]);
        *reinterpret_cast<bf16x8*>(&Bl[srow][scol]) =
            *reinterpret_cast<const bf16x8*>(&Wt[(size_t)(c0 + srow) * C_ + k0 + scol]);
        __syncthreads();
        bf16x8 af = *reinterpret_cast<const bf16x8*>(&Al[w * 16 + li][lg * 8]);
#pragma unroll
        for (int ct = 0; ct < 4; ++ct) {
            bf16x8 bf = *reinterpret_cast<const bf16x8*>(&Bl[ct * 16 + li][lg * 8]);
            acc[ct] = mfma16(af, bf, acc[ct]);
        }
        __syncthreads();
    }
    int mb = m0 + w * 16 + lg * 4;
    int b = mb >> 12, n = mb & 4095;
#pragma unroll
    for (int ct = 0; ct < 4; ++ct) {
        int col = c0 + ct * 16 + li;
        float bias = bqkv[col];
        int sec = col >> 8, cc = col & 255;
        int h = cc >> 5, d = cc & 31;
        if (sec == 2) {              // V stored transposed: Vt[b,h][d][n]
            PK4 pk;
#pragma unroll
            for (int r = 0; r < 4; ++r) pk.h[r] = (bf16_t)(acc[ct][r] + bias);
            *reinterpret_cast<uint2*>(&Vt[((size_t)((b << 3) + h) * 32 + d) * N_ + n]) = pk.u2;
        } else {                     // Q / K: [b,h][n][d]
            bf16_t* dst = (sec == 0) ? Q : K;
            size_t base = ((size_t)((b << 3) + h) * N_ + n) * 32 + d;
#pragma unroll
            for (int r = 0; r < 4; ++r) dst[base + (size_t)r * 32] = (bf16_t)(acc[ct][r] + bias);
        }
    }
}

// ---------------- flash attention: 32x32 MFMA, in-register P (T12), defer-max (T13),
// ---------------- 32-j chunked softmax to fit the 128-reg / 4-waves-per-SIMD budget ----------------
__global__ __launch_bounds__(256, 4) void attn(
    const bf16_t* __restrict__ Q, const bf16_t* __restrict__ Kg,
    const bf16_t* __restrict__ Vt, bf16_t* __restrict__ O)
{
    __shared__ __align__(16) bf16_t Kl[64][36];   // K[j][d]
    __shared__ __align__(16) bf16_t Vl[32][68];   // V^T[d][j]
    int id = blockIdx.x;
    int wg = (id & 7) * 128 + (id >> 3);          // XCD swizzle
    int bh = wg >> 5, qb = wg & 31;
    int t = threadIdx.x, w = t >> 6, l = t & 63;
    int lo = l & 31, hi = l >> 5;
    const bf16_t* Qp = Q + (size_t)bh * N_ * 32;
    const bf16_t* Kp = Kg + (size_t)bh * N_ * 32;
    const bf16_t* Vp = Vt + (size_t)bh * 32 * N_;
    int qrow = qb * 128 + w * 32 + lo;
    bf16x8 qf0 = *reinterpret_cast<const bf16x8*>(&Qp[(size_t)qrow * 32 + hi * 8]);
    bf16x8 qf1 = *reinterpret_cast<const bf16x8*>(&Qp[(size_t)qrow * 32 + 16 + hi * 8]);
    f32x16 oacc = {};
    float m_run = -INFINITY, l_run = 0.f;
    int krow = t >> 2, kcol = (t & 3) * 8;
    int vrow = t >> 3, vcol = (t & 7) * 8;
    const bf16_t* kgp = Kp + (size_t)krow * 32 + kcol;
    const bf16_t* vgp = Vp + (size_t)vrow * N_ + vcol;
    bf16x8 kreg = *reinterpret_cast<const bf16x8*>(kgp);
    bf16x8 vreg = *reinterpret_cast<const bf16x8*>(vgp);
    for (int n0 = 0; n0 < N_; n0 += 64) {
        *reinterpret_cast<bf16x8*>(&Kl[krow][kcol]) = kreg;
        *reinterpret_cast<bf16x8*>(&Vl[vrow][vcol]) = vreg;
        __syncthreads();
        if (n0 + 64 < N_) {                       // issue next tile's loads early (T14)
            kgp += 64 * 32; vgp += 64;
            kreg = *reinterpret_cast<const bf16x8*>(kgp);
            vreg = *reinterpret_cast<const bf16x8*>(vgp);
        }
        // two 32-j chunks, each a full online-softmax step (keeps live regs ~95)
#pragma unroll
        for (int c = 0; c < 2; ++c) {
            bf16x8 kfA = *reinterpret_cast<const bf16x8*>(&Kl[c * 32 + lo][hi * 8]);
            bf16x8 kfB = *reinterpret_cast<const bf16x8*>(&Kl[c * 32 + lo][16 + hi * 8]);
            f32x16 st = {};
            __builtin_amdgcn_s_setprio(1);
            st = mfma32(kfA, qf0, st);
            st = mfma32(kfB, qf1, st);
            __builtin_amdgcn_s_setprio(0);
            // chunk max over 32 j: 16 in-lane + partner half
            float m0a = fmaxf(fmaxf(st[0], st[1]), fmaxf(st[2], st[3]));
            float m0b = fmaxf(fmaxf(st[4], st[5]), fmaxf(st[6], st[7]));
            float m0c = fmaxf(fmaxf(st[8], st[9]), fmaxf(st[10], st[11]));
            float m0d = fmaxf(fmaxf(st[12], st[13]), fmaxf(st[14], st[15]));
            float mloc = xhalf_max(fmaxf(fmaxf(m0a, m0b), fmaxf(m0c, m0d)));
            if (!__all(mloc - m_run <= DMTHR)) {   // defer-max (T13)
                float m_new = fmaxf(m_run, mloc);
                float alpha = __builtin_amdgcn_exp2f((m_run - m_new) * AEXP);
                m_run = m_new;
                l_run *= alpha;
#pragma unroll
                for (int u = 0; u < 16; ++u) oacc[u] *= alpha;
            }
            float msc = m_run * AEXP;
            float lsum = 0.f;
#pragma unroll
            for (int u = 0; u < 16; ++u) {
                st[u] = __builtin_amdgcn_exp2f(fmaf(st[u], AEXP, -msc));
                lsum += st[u];
            }
            l_run += xhalf_sum(lsum);
            bf16x8 pf0 = mkfrag(st[0], st[1], st[2], st[3], st[4], st[5], st[6], st[7]);
            bf16x8 pf1 = mkfrag(st[8], st[9], st[10], st[11], st[12], st[13], st[14], st[15]);
            bf16x8 vfA = *reinterpret_cast<const bf16x8*>(&Vl[lo][c * 32 + hi * 8]);
            bf16x8 vfB = *reinterpret_cast<const bf16x8*>(&Vl[lo][c * 32 + 16 + hi * 8]);
            __builtin_amdgcn_s_setprio(1);
            oacc = mfma32(vfA, pf0, oacc);
            oacc = mfma32(vfB, pf1, oacc);
            __builtin_amdgcn_s_setprio(0);
        }
        __syncthreads();
    }
    // epilogue: O^T[d][i] / l(i) -> O[b][n][h*32+d]; d = rq*8 + hi*4 + (reg&3)
    float inv_l = 1.f / l_run;
    int b = bh >> 3, h = bh & 7;
#pragma unroll
    for (int rq = 0; rq < 4; ++rq) {
        PK4 pk;
#pragma unroll
        for (int r = 0; r < 4; ++r) pk.h[r] = (bf16_t)(oacc[rq * 4 + r] * inv_l);
        int d = rq * 8 + hi * 4;
        *reinterpret_cast<uint2*>(&O[(((size_t)b * N_ + qrow) * 8 + h) * 32 + d]) = pk.u2;
    }
}

// ---------------- proj GEMM + bias + residual(x) -> z [B,C,N] f32, + group partial sums ----------------
__global__ __launch_bounds__(256) void gemm_proj(
    const bf16_t* __restrict__ O, const bf16_t* __restrict__ Wpt,
    const float* __restrict__ bproj, const float* __restrict__ x,
    float* __restrict__ z, float* __restrict__ stats)
{
    __shared__ __align__(16) bf16_t Al[64][40];
    __shared__ __align__(16) bf16_t Bl[64][40];
    int m0 = blockIdx.x * 64, c0 = blockIdx.y * 64;
    int t = threadIdx.x;
    int w = t >> 6, l = t & 63, li = l & 15, lg = l >> 4;
    int srow = t >> 2, scol = (t & 3) * 8;
    f32x4 acc[4] = {};
    for (int k0 = 0; k0 < C_; k0 += 32) {
        *reinterpret_cast<bf16x8*>(&Al[srow][scol]) =
            *reinterpret_cast<const bf16x8*>(&O[(size_t)(m0 + srow) * C_ + k0 + scol]);
        *reinterpret_cast<bf16x8*>(&Bl[srow][scol]) =
            *reinterpret_cast<const bf16x8*>(&Wpt[(size_t)(c0 + srow) * C_ + k0 + scol]);
        __syncthreads();
        bf16x8 af = *reinterpret_cast<const bf16x8*>(&Al[w * 16 + li][lg * 8]);
#pragma unroll
        for (int ct = 0; ct < 4; ++ct) {
            bf16x8 bf = *reinterpret_cast<const bf16x8*>(&Bl[ct * 16 + li][lg * 8]);
            acc[ct] = mfma16(af, bf, acc[ct]);
        }
        __syncthreads();
    }
    int mb = m0 + w * 16 + lg * 4;
    int b = mb >> 12, n = mb & 4095;
#pragma unroll
    for (int ct = 0; ct < 4; ++ct) {
        int c = c0 + ct * 16 + li;
        float bias = bproj[c];
        size_t xoff = ((size_t)b * C_ + c) * N_ + n;
        f32x4 xv = *reinterpret_cast<const f32x4*>(&x[xoff]);
        f32x4 zv;
        float s = 0.f, s2 = 0.f;
#pragma unroll
        for (int r = 0; r < 4; ++r) {
            float v = acc[ct][r] + bias + xv[r];
            zv[r] = v; s += v; s2 += v * v;
        }
        *reinterpret_cast<f32x4*>(&z[xoff]) = zv;
        s  += __shfl_xor(s, 16, 64);  s  += __shfl_xor(s, 32, 64);
        s2 += __shfl_xor(s2, 16, 64); s2 += __shfl_xor(s2, 32, 64);
        s  += __shfl_xor(s, 1, 64);  s  += __shfl_xor(s, 2, 64);  s  += __shfl_xor(s, 4, 64);
        s2 += __shfl_xor(s2, 1, 64); s2 += __shfl_xor(s2, 2, 64); s2 += __shfl_xor(s2, 4, 64);
        if (lg == 0 && (li & 7) == 0) {
            int g = c >> 3;
            atomicAdd(&stats[((b << 5) + g) * 2 + 0], s);
            atomicAdd(&stats[((b << 5) + g) * 2 + 1], s2);
        }
    }
}

// ---------------- GroupNorm normalize: z [B,C,N] -> out [B,C,H,W] ----------------
__global__ void gnorm(const float* __restrict__ z, const float* __restrict__ stats,
                      const float* __restrict__ gamma, const float* __restrict__ beta,
                      float* __restrict__ out)
{
    size_t idx = ((size_t)blockIdx.x * 256 + threadIdx.x) * 4;
    int b = (int)(idx >> 20);
    int c = (int)((idx >> 12) & 255);
    int g = c >> 3;
    float s = stats[((b << 5) + g) * 2], s2 = stats[((b << 5) + g) * 2 + 1];
    const float inv = 1.f / 32768.f;
    float mean = s * inv;
    float var = s2 * inv - mean * mean;
    float rs = rsqrtf(var + 1e-5f);
    float ga = gamma[c] * rs;
    float be = beta[c];
    f32x4 v = *reinterpret_cast<const f32x4*>(&z[idx]);
    f32x4 o;
#pragma unroll
    for (int r = 0; r < 4; ++r) o[r] = (v[r] - mean) * ga + be;
    *reinterpret_cast<f32x4*>(&out[idx]) = o;
}

extern "C" void kernel_launch(void* const* d_in, const int* in_sizes, int n_in,
                              void* d_out, int out_size, void* d_ws, size_t ws_size,
                              hipStream_t stream) {
    (void)in_sizes; (void)n_in; (void)out_size; (void)ws_size;
    const float* x     = (const float*)d_in[0];
    const float* wqkv  = (const float*)d_in[1];
    const float* bqkv  = (const float*)d_in[2];
    const float* wproj = (const float*)d_in[3];
    const float* bproj = (const float*)d_in[4];
    const float* gamma = (const float*)d_in[5];
    const float* beta  = (const float*)d_in[6];
    float* out = (float*)d_out;

    char* ws = (char*)d_ws;
    const size_t SZ_BNC2 = (size_t)B_ * N_ * C_ * 2;
    size_t off = 0;
    bf16_t* xT  = (bf16_t*)(ws + off); off += SZ_BNC2;
    bf16_t* Wt  = (bf16_t*)(ws + off); off += (size_t)D3_ * C_ * 2;
    bf16_t* Qb  = (bf16_t*)(ws + off); off += SZ_BNC2;
    bf16_t* Kb  = (bf16_t*)(ws + off); off += SZ_BNC2;
    bf16_t* Vtb = (bf16_t*)(ws + off); off += SZ_BNC2;
    bf16_t* Ob  = (bf16_t*)(ws + off); off += SZ_BNC2;
    bf16_t* Wpt = (bf16_t*)(ws + off); off += (size_t)C_ * C_ * 2;
    float*  stats = (float*)(ws + off); off += 1024;
    float* zb = (float*)d_ws;   // aliases xT/Wt/Qb (dead by gemm_proj)

    prep_w <<<768, 256, 0, stream>>>(wqkv, wproj, Wt, Wpt, stats);
    prep_xt<<<dim3(N_ / 32, C_ / 32, B_), 256, 0, stream>>>(x, xT);
    gemm_qkv<<<dim3(256, 12), 256, 0, stream>>>(xT, Wt, bqkv, Qb, Kb, Vtb);
    attn<<<1024, 256, 0, stream>>>(Qb, Kb, Vtb, Ob);
    gemm_proj<<<dim3(256, 4), 256, 0, stream>>>(Ob, Wpt, bproj, x, zb, stats);
    gnorm<<<4096, 256, 0, stream>>>(zb, stats, gamma, beta, out);
}